// Round 7
// baseline (101.228 us; speedup 1.0000x reference)
//
#include <hip/hip_runtime.h>
#include <hip/hip_bf16.h>
#include <math.h>

// Problem constants (fixed by setup_inputs)
constexpr int N  = 64;
constexpr int V  = 25;
constexpr int K  = 3;
constexpr int CT = 32768;            // C*T
constexpr int VK = 12;               // int(0.5 * 25)
constexpr int SPLIT = 32;            // score-pass split along ct per sample
constexpr int ROWS  = 256;           // rows per LDS tile (64 rows per wave)
constexpr int CHUNK = CT / SPLIT;    // 1024
constexpr int TILES = CHUNK / ROWS;  // 4
constexpr int NBLK_G = N * (CT / ROWS);   // 8192 gather blocks

typedef float f32x4 __attribute__((ext_vector_type(4)));   // NT-store-legal float4

// ---------------- ws layout (bytes) ----------------
// partial_t : N*V*SPLIT floats = 51200 @ 0       (204800 B)  layout [n][v][s]
// p2partial : SPLIT floats @ 204800               (128 B)
// y_hat     : N*VK floats @ 204928                (3072 B)
// idx       : N*VK ints  @ 208000                 (3072 B)
// xc        : N*V*CT ushorts (bf16, transposed) @ 212992  (104857600 B)  [optional]
constexpr size_t XC_OFF   = 212992;
constexpr size_t XC_BYTES = (size_t)N * V * CT * sizeof(ushort);

__device__ __forceinline__ ushort f2bf(float f) {       // RNE float->bf16
    unsigned u = __float_as_uint(f);
    u += 0x7FFFu + ((u >> 16) & 1u);
    return (ushort)(u >> 16);
}
__device__ __forceinline__ float bf2f(ushort us) {
    return __uint_as_float((unsigned)us << 16);
}

__device__ __forceinline__ void gload_lds16(const float* g, float* l) {
    // async global->LDS DMA: 16B per lane; LDS dest = wave-uniform base + lane*16
    __builtin_amdgcn_global_load_lds(
        (const __attribute__((address_space(1))) void*)g,
        (__attribute__((address_space(3))) void*)l, 16, 0, 0);
}

// Wave stages its own 64 rows (1600 floats = 400 float4s). Region is wave-exclusive.
__device__ __forceinline__ void stage_wave(const float* __restrict__ gsrc, float* ldsbuf,
                                           int wave, int lane) {
    const float* gw = gsrc + (size_t)wave * 1600;
    float* lw = ldsbuf + wave * 1600;
    #pragma unroll
    for (int i = 0; i < 6; ++i)
        gload_lds16(gw + (size_t)(i * 64 + lane) * 4, lw + i * 256);
    if (lane < 16)
        gload_lds16(gw + (size_t)(384 + lane) * 4, lw + 384 * 4);
}

// Phase 1: partial raw dots + (optionally) bf16 transposed copy xc[n][v][ct].
// Barrier-free tile loop (per-wave LDS regions, per-wave vmcnt sync).
template <bool WRITE_XC>
__global__ __launch_bounds__(256) void k_scores(const float* __restrict__ x,
                                                const float* __restrict__ p,
                                                float* __restrict__ partial_t,
                                                float* __restrict__ p2partial,
                                                ushort* __restrict__ xc) {
    const int n = blockIdx.x / SPLIT;
    const int s = blockIdx.x % SPLIT;
    const int ct0 = s * CHUNK;
    const float* xn = x + (size_t)n * CT * V;
    ushort* xcn = xc + (size_t)n * V * CT;
    const int tid = threadIdx.x, wave = tid >> 6, lane = tid & 63;

    __shared__ float lds[ROWS * V];       // 25600 B

    float acc[V];
    #pragma unroll
    for (int v = 0; v < V; ++v) acc[v] = 0.f;
    float psq = 0.f;

    for (int tile = 0; tile < TILES; ++tile) {
        const int base_ct = ct0 + tile * ROWS;
        // WAR: prior ds_reads of this wave's region must retire before DMA overwrites
        asm volatile("s_waitcnt lgkmcnt(0)" ::: "memory");
        stage_wave(xn + (size_t)base_ct * V, lds, wave, lane);
        asm volatile("s_waitcnt vmcnt(0)" ::: "memory");

        const float pv = p[base_ct + tid];
        psq += pv * pv;
        const float* row = lds + tid * V;   // stride 25: bank-conflict-free
        #pragma unroll
        for (int v = 0; v < V; ++v) acc[v] += row[v] * pv;

        if (WRITE_XC) {
            // transposed bf16 copy: per v, 64 lanes write 128 contiguous bytes
            #pragma unroll
            for (int v = 0; v < V; ++v)
                xcn[(size_t)v * CT + base_ct + tid] = f2bf(row[v]);
        }
    }

    #pragma unroll
    for (int v = 0; v < V; ++v) {
        float a = acc[v];
        #pragma unroll
        for (int off = 32; off > 0; off >>= 1) a += __shfl_down(a, off);
        acc[v] = a;
    }
    #pragma unroll
    for (int off = 32; off > 0; off >>= 1) psq += __shfl_down(psq, off);

    __shared__ float red[4][V];
    __shared__ float redp[4];
    if (lane == 0) {
        #pragma unroll
        for (int v = 0; v < V; ++v) red[wave][v] = acc[v];
        redp[wave] = psq;
    }
    __syncthreads();
    if (tid < V) {
        partial_t[((size_t)n * V + tid) * SPLIT + s] =
            red[0][tid] + red[1][tid] + red[2][tid] + red[3][tid];
    }
    if (tid == V && n == 0) {
        p2partial[s] = redp[0] + redp[1] + redp[2] + redp[3];
    }
}

// Top-12 per sample (stable desc on raw sums — monotone-equivalent under the
// positive normalization scale), y_hat = sigmoid(normalized). 64 x 64.
__global__ __launch_bounds__(64) void k_topk(const float* __restrict__ partial_t,
                                             const float* __restrict__ p2partial,
                                             int* __restrict__ idxbuf,
                                             float* __restrict__ yhatbuf) {
    const int n = blockIdx.x, lane = threadIdx.x;
    float s2 = 0.f;
    #pragma unroll
    for (int i = 0; i < SPLIT; ++i) s2 += p2partial[i];

    float my = 0.f;
    if (lane < V) {
        const float4* pb = (const float4*)(partial_t + ((size_t)n * V + lane) * SPLIT);
        #pragma unroll
        for (int i = 0; i < SPLIT / 4; ++i) {
            float4 q = pb[i];
            my += q.x + q.y + q.z + q.w;
        }
    }
    int rank = 0;
    #pragma unroll
    for (int u = 0; u < V; ++u) {
        const float yu = __shfl(my, u);
        if (yu > my || (yu == my && u < lane)) ++rank;
    }
    if (lane < V && rank < VK) {
        idxbuf[n * VK + rank]  = lane;
        yhatbuf[n * VK + rank] = 1.0f / (1.0f + expf(-my * rsqrtf(s2)));
    }
}

// Phase 2 (fast path): gather from the bf16 transposed copy — reads ONLY the 12
// kept rows (50 MB instead of 210 MB). Coalesced remapped NT stores.
// blocks [0,8192): x_out. blocks [8192,8384): A_out (wave 0).
__global__ __launch_bounds__(256) void k_gather_xc(const ushort* __restrict__ xc,
                                                   const float* __restrict__ A,
                                                   const int* __restrict__ idxbuf,
                                                   const float* __restrict__ yhatbuf,
                                                   float* __restrict__ xout,
                                                   float* __restrict__ aout) {
    __shared__ int   sidx[VK];
    __shared__ float syh[VK];
    const int tid = threadIdx.x, wave = tid >> 6, lane = tid & 63;

    if (blockIdx.x < (unsigned)NBLK_G) {
        const int n  = blockIdx.x >> 7;
        const int r0 = (blockIdx.x & 127) << 8;   // ct base, 256-aligned
        if (tid < VK) {
            sidx[tid] = idxbuf[n * VK + tid];
            syh[tid]  = yhatbuf[n * VK + tid];
        }
        __syncthreads();

        const ushort* xcn = xc + (size_t)n * V * CT + r0;
        f32x4* dst = (f32x4*)(xout + ((size_t)n * CT + r0) * VK);
        // output tile = 256 rows x 12 floats = 768 f4s; thread writes f = tid+256j
        #pragma unroll
        for (int j = 0; j < 3; ++j) {
            const int f   = tid + j * 256;
            const int row = f / 3;              // ct offset within tile
            const int c0  = (f % 3) * 4;
            f32x4 o;
            o.x = bf2f(xcn[(size_t)sidx[c0 + 0] * CT + row]) * syh[c0 + 0];
            o.y = bf2f(xcn[(size_t)sidx[c0 + 1] * CT + row]) * syh[c0 + 1];
            o.z = bf2f(xcn[(size_t)sidx[c0 + 2] * CT + row]) * syh[c0 + 2];
            o.w = bf2f(xcn[(size_t)sidx[c0 + 3] * CT + row]) * syh[c0 + 3];
            __builtin_nontemporal_store(o, &dst[f]);   // lane-contiguous: coalesced
        }
    } else {
        if (wave != 0) return;
        __shared__ float ldsA[V * V];
        const int b2 = blockIdx.x - NBLK_G;      // [0, 192)
        const int n  = b2 / K;
        const int k  = b2 % K;
        if (lane < VK) sidx[lane] = idxbuf[n * VK + lane];
        const float* Ak = A + ((size_t)n * K + k) * V * V;
        for (int i = lane; i < V * V; i += 64) ldsA[i] = Ak[i];
        asm volatile("s_waitcnt vmcnt(0) lgkmcnt(0)" ::: "memory");
        for (int o = lane; o < VK * VK; o += 64) {
            const int a  = o / VK, bc = o % VK;
            const int ia = sidx[a], ib = sidx[bc];
            float ssum = 0.f;
            #pragma unroll
            for (int m = 0; m < V; ++m) ssum += ldsA[ia * V + m] * ldsA[m * V + ib];
            __builtin_nontemporal_store(ssum, &aout[((size_t)n * K + k) * VK * VK + o]);
        }
    }
}

// Fallback phase 2 (ws too small for xc): round-6 structure, re-reads fp32 x.
__global__ __launch_bounds__(256) void k_gather_aout(const float* __restrict__ x,
                                                     const float* __restrict__ A,
                                                     const int* __restrict__ idxbuf,
                                                     const float* __restrict__ yhatbuf,
                                                     float* __restrict__ xout,
                                                     float* __restrict__ aout) {
    __shared__ float lds[ROWS * V];
    __shared__ int   swidx[4][VK];
    __shared__ float swyh[4][VK];
    const int tid = threadIdx.x, wave = tid >> 6, lane = tid & 63;

    if (blockIdx.x < (unsigned)NBLK_G) {
        const int n  = blockIdx.x >> 7;
        const int r0 = (blockIdx.x & 127) << 8;
        stage_wave(x + ((size_t)n * CT + r0) * V, lds, wave, lane);
        if (lane < VK) {
            swidx[wave][lane] = idxbuf[n * VK + lane];
            swyh[wave][lane]  = yhatbuf[n * VK + lane];
        }
        asm volatile("s_waitcnt vmcnt(0) lgkmcnt(0)" ::: "memory");
        f32x4* dst = (f32x4*)(xout + ((size_t)n * CT + r0) * VK);
        #pragma unroll
        for (int j = 0; j < 3; ++j) {
            const int f   = 192 * wave + 64 * j + lane;
            const int row = f / 3;
            const int c0  = (f % 3) * 4;
            f32x4 o;
            o.x = lds[row * V + swidx[wave][c0 + 0]] * swyh[wave][c0 + 0];
            o.y = lds[row * V + swidx[wave][c0 + 1]] * swyh[wave][c0 + 1];
            o.z = lds[row * V + swidx[wave][c0 + 2]] * swyh[wave][c0 + 2];
            o.w = lds[row * V + swidx[wave][c0 + 3]] * swyh[wave][c0 + 3];
            __builtin_nontemporal_store(o, &dst[f]);
        }
    } else {
        if (wave != 0) return;
        const int b2 = blockIdx.x - NBLK_G;
        const int n  = b2 / K;
        const int k  = b2 % K;
        if (lane < VK) swidx[0][lane] = idxbuf[n * VK + lane];
        const float* Ak = A + ((size_t)n * K + k) * V * V;
        for (int i = lane; i < V * V; i += 64) lds[i] = Ak[i];
        asm volatile("s_waitcnt vmcnt(0) lgkmcnt(0)" ::: "memory");
        for (int o = lane; o < VK * VK; o += 64) {
            const int a  = o / VK, bc = o % VK;
            const int ia = swidx[0][a], ib = swidx[0][bc];
            float ssum = 0.f;
            #pragma unroll
            for (int m = 0; m < V; ++m) ssum += lds[ia * V + m] * lds[m * V + ib];
            __builtin_nontemporal_store(ssum, &aout[((size_t)n * K + k) * VK * VK + o]);
        }
    }
}

extern "C" void kernel_launch(void* const* d_in, const int* in_sizes, int n_in,
                              void* d_out, int out_size, void* d_ws, size_t ws_size,
                              hipStream_t stream) {
    const float* x = (const float*)d_in[0];
    const float* A = (const float*)d_in[1];
    const float* p = (const float*)d_in[2];

    float* xout = (float*)d_out;                       // N*CT*VK floats
    float* aout = xout + (size_t)N * CT * VK;          // N*K*VK*VK floats

    char* ws = (char*)d_ws;
    float* partial_t = (float*)(ws);                   // 51200 floats [n][v][s]
    float* p2partial = (float*)(ws + 204800);          // 32 floats
    float* yhatbuf   = (float*)(ws + 204928);          // 768 floats
    int*   idxbuf    = (int*)  (ws + 208000);          // 768 ints
    ushort* xc       = (ushort*)(ws + XC_OFF);         // bf16 transposed copy

    const bool use_xc = ws_size >= XC_OFF + XC_BYTES;

    if (use_xc) {
        k_scores<true><<<N * SPLIT, 256, 0, stream>>>(x, p, partial_t, p2partial, xc);
        k_topk<<<N, 64, 0, stream>>>(partial_t, p2partial, idxbuf, yhatbuf);
        k_gather_xc<<<NBLK_G + N * K, 256, 0, stream>>>(xc, A, idxbuf, yhatbuf, xout, aout);
    } else {
        k_scores<false><<<N * SPLIT, 256, 0, stream>>>(x, p, partial_t, p2partial, xc);
        k_topk<<<N, 64, 0, stream>>>(partial_t, p2partial, idxbuf, yhatbuf);
        k_gather_aout<<<NBLK_G + N * K, 256, 0, stream>>>(x, A, idxbuf, yhatbuf, xout, aout);
    }
}

// Round 8
// 100.876 us; speedup vs baseline: 1.0035x; 1.0035x over previous
//
#include <hip/hip_runtime.h>
#include <hip/hip_bf16.h>
#include <math.h>

// Problem constants (fixed by setup_inputs)
constexpr int N  = 64;
constexpr int V  = 25;
constexpr int K  = 3;
constexpr int CT = 32768;            // C*T
constexpr int VK = 12;               // int(0.5 * 25)
constexpr int SPLIT = 32;            // score-pass split along ct per sample
constexpr int ROWS  = 256;           // rows per LDS tile (64 rows per wave)
constexpr int CHUNK = CT / SPLIT;    // 1024
constexpr int TILES = CHUNK / ROWS;  // 4
constexpr int NBLK_G = N * (CT / ROWS);   // 8192 gather blocks

typedef float f32x4 __attribute__((ext_vector_type(4)));   // NT-store-legal float4

// ---------------- ws layout (bytes) ----------------
// partial_t : N*V*SPLIT floats = 51200 @ 0       (204800 B)  layout [n][v][s]
// p2partial : SPLIT floats @ 204800               (128 B)
// y_hat     : N*VK floats @ 204928                (3072 B)
// idx       : N*VK ints  @ 208000                 (3072 B)
// xc        : N*V*CT ushorts (bf16, transposed) @ 212992  (104857600 B)  [optional]
constexpr size_t XC_OFF   = 212992;
constexpr size_t XC_BYTES = (size_t)N * V * CT * sizeof(ushort);

__device__ __forceinline__ float bf2f(ushort us) {
    return __uint_as_float((unsigned)us << 16);
}

__device__ __forceinline__ void gload_lds16(const float* g, float* l) {
    // async global->LDS DMA: 16B per lane; LDS dest = wave-uniform base + lane*16
    __builtin_amdgcn_global_load_lds(
        (const __attribute__((address_space(1))) void*)g,
        (__attribute__((address_space(3))) void*)l, 16, 0, 0);
}

// Wave stages its own 64 rows (1600 floats = 400 float4s). Region is wave-exclusive.
__device__ __forceinline__ void stage_wave(const float* __restrict__ gsrc, float* ldsbuf,
                                           int wave, int lane) {
    const float* gw = gsrc + (size_t)wave * 1600;
    float* lw = ldsbuf + wave * 1600;
    #pragma unroll
    for (int i = 0; i < 6; ++i)
        gload_lds16(gw + (size_t)(i * 64 + lane) * 4, lw + i * 256);
    if (lane < 16)
        gload_lds16(gw + (size_t)(384 + lane) * 4, lw + 384 * 4);
}

// Phase 1: partial raw dots + (optionally) PACKED bf16 transposed copy xc[n][v][ct].
// Barrier-free tile loop (per-wave LDS regions, per-wave vmcnt/lgkmcnt sync).
template <bool WRITE_XC>
__global__ __launch_bounds__(256) void k_scores(const float* __restrict__ x,
                                                const float* __restrict__ p,
                                                float* __restrict__ partial_t,
                                                float* __restrict__ p2partial,
                                                ushort* __restrict__ xc) {
    const int n = blockIdx.x / SPLIT;
    const int s = blockIdx.x % SPLIT;
    const int ct0 = s * CHUNK;
    const float* xn = x + (size_t)n * CT * V;
    ushort* xcn = xc + (size_t)n * V * CT;
    const int tid = threadIdx.x, wave = tid >> 6, lane = tid & 63;

    __shared__ float lds[ROWS * V];       // 25600 B

    float acc[V];
    #pragma unroll
    for (int v = 0; v < V; ++v) acc[v] = 0.f;
    float psq = 0.f;

    for (int tile = 0; tile < TILES; ++tile) {
        const int base_ct = ct0 + tile * ROWS;
        // WAR: this wave's ds_reads (acc + transpose) must retire before DMA overwrite
        asm volatile("s_waitcnt lgkmcnt(0)" ::: "memory");
        stage_wave(xn + (size_t)base_ct * V, lds, wave, lane);
        asm volatile("s_waitcnt vmcnt(0)" ::: "memory");

        const float pv = p[base_ct + tid];
        psq += pv * pv;
        const float* row = lds + tid * V;   // stride 25: bank-conflict-free
        #pragma unroll
        for (int v = 0; v < V; ++v) acc[v] += row[v] * pv;

        if (WRITE_XC) {
            // Per-wave packed transpose of its OWN 64 rows (rows 64*wave..64*wave+63):
            // 200 pairs (v, oct_local); 8 stride-25 LDS reads (<=2-way banks),
            // 4x v_cvt_pk_bf16_f32, one 16-B store (lanes form 128-B segments).
            const float* wrows = lds + wave * 64 * V;
            for (int pq = lane; pq < V * 8; pq += 64) {
                const int v     = pq >> 3;
                const int oct_l = pq & 7;
                const float* src = wrows + oct_l * 8 * V + v;
                unsigned u0, u1, u2, u3;
                asm("v_cvt_pk_bf16_f32 %0, %1, %2" : "=v"(u0) : "v"(src[0 * V]), "v"(src[1 * V]));
                asm("v_cvt_pk_bf16_f32 %0, %1, %2" : "=v"(u1) : "v"(src[2 * V]), "v"(src[3 * V]));
                asm("v_cvt_pk_bf16_f32 %0, %1, %2" : "=v"(u2) : "v"(src[4 * V]), "v"(src[5 * V]));
                asm("v_cvt_pk_bf16_f32 %0, %1, %2" : "=v"(u3) : "v"(src[6 * V]), "v"(src[7 * V]));
                uint4 pk = make_uint4(u0, u1, u2, u3);
                const int oct = wave * 8 + oct_l;           // global octet in tile
                *(uint4*)(xcn + (size_t)v * CT + base_ct + oct * 8) = pk;  // 16B aligned
            }
        }
    }

    #pragma unroll
    for (int v = 0; v < V; ++v) {
        float a = acc[v];
        #pragma unroll
        for (int off = 32; off > 0; off >>= 1) a += __shfl_down(a, off);
        acc[v] = a;
    }
    #pragma unroll
    for (int off = 32; off > 0; off >>= 1) psq += __shfl_down(psq, off);

    __shared__ float red[4][V];
    __shared__ float redp[4];
    if (lane == 0) {
        #pragma unroll
        for (int v = 0; v < V; ++v) red[wave][v] = acc[v];
        redp[wave] = psq;
    }
    __syncthreads();
    if (tid < V) {
        partial_t[((size_t)n * V + tid) * SPLIT + s] =
            red[0][tid] + red[1][tid] + red[2][tid] + red[3][tid];
    }
    if (tid == V && n == 0) {
        p2partial[s] = redp[0] + redp[1] + redp[2] + redp[3];
    }
}

// Top-12 per sample (stable desc on raw sums — monotone-equivalent under the
// positive normalization scale), y_hat = sigmoid(normalized). 64 x 64.
__global__ __launch_bounds__(64) void k_topk(const float* __restrict__ partial_t,
                                             const float* __restrict__ p2partial,
                                             int* __restrict__ idxbuf,
                                             float* __restrict__ yhatbuf) {
    const int n = blockIdx.x, lane = threadIdx.x;
    float s2 = 0.f;
    #pragma unroll
    for (int i = 0; i < SPLIT; ++i) s2 += p2partial[i];

    float my = 0.f;
    if (lane < V) {
        const float4* pb = (const float4*)(partial_t + ((size_t)n * V + lane) * SPLIT);
        #pragma unroll
        for (int i = 0; i < SPLIT / 4; ++i) {
            float4 q = pb[i];
            my += q.x + q.y + q.z + q.w;
        }
    }
    int rank = 0;
    #pragma unroll
    for (int u = 0; u < V; ++u) {
        const float yu = __shfl(my, u);
        if (yu > my || (yu == my && u < lane)) ++rank;
    }
    if (lane < V && rank < VK) {
        idxbuf[n * VK + rank]  = lane;
        yhatbuf[n * VK + rank] = 1.0f / (1.0f + expf(-my * rsqrtf(s2)));
    }
}

// Phase 2 (fast path): gather from the bf16 transposed copy — reads ONLY the 12
// kept rows (50 MB instead of 210 MB). Coalesced remapped NT stores.
// blocks [0,8192): x_out. blocks [8192,8384): A_out (wave 0).
__global__ __launch_bounds__(256) void k_gather_xc(const ushort* __restrict__ xc,
                                                   const float* __restrict__ A,
                                                   const int* __restrict__ idxbuf,
                                                   const float* __restrict__ yhatbuf,
                                                   float* __restrict__ xout,
                                                   float* __restrict__ aout) {
    __shared__ int   sidx[VK];
    __shared__ float syh[VK];
    const int tid = threadIdx.x, wave = tid >> 6, lane = tid & 63;

    if (blockIdx.x < (unsigned)NBLK_G) {
        const int n  = blockIdx.x >> 7;
        const int r0 = (blockIdx.x & 127) << 8;   // ct base, 256-aligned
        if (tid < VK) {
            sidx[tid] = idxbuf[n * VK + tid];
            syh[tid]  = yhatbuf[n * VK + tid];
        }
        __syncthreads();

        const ushort* xcn = xc + (size_t)n * V * CT + r0;
        f32x4* dst = (f32x4*)(xout + ((size_t)n * CT + r0) * VK);
        // output tile = 256 rows x 12 floats = 768 f4s; thread writes f = tid+256j
        #pragma unroll
        for (int j = 0; j < 3; ++j) {
            const int f   = tid + j * 256;
            const int row = f / 3;              // ct offset within tile
            const int c0  = (f % 3) * 4;
            f32x4 o;
            o.x = bf2f(xcn[(size_t)sidx[c0 + 0] * CT + row]) * syh[c0 + 0];
            o.y = bf2f(xcn[(size_t)sidx[c0 + 1] * CT + row]) * syh[c0 + 1];
            o.z = bf2f(xcn[(size_t)sidx[c0 + 2] * CT + row]) * syh[c0 + 2];
            o.w = bf2f(xcn[(size_t)sidx[c0 + 3] * CT + row]) * syh[c0 + 3];
            __builtin_nontemporal_store(o, &dst[f]);   // lane-contiguous: coalesced
        }
    } else {
        if (wave != 0) return;
        __shared__ float ldsA[V * V];
        const int b2 = blockIdx.x - NBLK_G;      // [0, 192)
        const int n  = b2 / K;
        const int k  = b2 % K;
        if (lane < VK) sidx[lane] = idxbuf[n * VK + lane];
        const float* Ak = A + ((size_t)n * K + k) * V * V;
        for (int i = lane; i < V * V; i += 64) ldsA[i] = Ak[i];
        asm volatile("s_waitcnt vmcnt(0) lgkmcnt(0)" ::: "memory");
        for (int o = lane; o < VK * VK; o += 64) {
            const int a  = o / VK, bc = o % VK;
            const int ia = sidx[a], ib = sidx[bc];
            float ssum = 0.f;
            #pragma unroll
            for (int m = 0; m < V; ++m) ssum += ldsA[ia * V + m] * ldsA[m * V + ib];
            __builtin_nontemporal_store(ssum, &aout[((size_t)n * K + k) * VK * VK + o]);
        }
    }
}

// Fallback phase 2 (ws too small for xc): round-6 structure, re-reads fp32 x.
__global__ __launch_bounds__(256) void k_gather_aout(const float* __restrict__ x,
                                                     const float* __restrict__ A,
                                                     const int* __restrict__ idxbuf,
                                                     const float* __restrict__ yhatbuf,
                                                     float* __restrict__ xout,
                                                     float* __restrict__ aout) {
    __shared__ float lds[ROWS * V];
    __shared__ int   swidx[4][VK];
    __shared__ float swyh[4][VK];
    const int tid = threadIdx.x, wave = tid >> 6, lane = tid & 63;

    if (blockIdx.x < (unsigned)NBLK_G) {
        const int n  = blockIdx.x >> 7;
        const int r0 = (blockIdx.x & 127) << 8;
        stage_wave(x + ((size_t)n * CT + r0) * V, lds, wave, lane);
        if (lane < VK) {
            swidx[wave][lane] = idxbuf[n * VK + lane];
            swyh[wave][lane]  = yhatbuf[n * VK + lane];
        }
        asm volatile("s_waitcnt vmcnt(0) lgkmcnt(0)" ::: "memory");
        f32x4* dst = (f32x4*)(xout + ((size_t)n * CT + r0) * VK);
        #pragma unroll
        for (int j = 0; j < 3; ++j) {
            const int f   = 192 * wave + 64 * j + lane;
            const int row = f / 3;
            const int c0  = (f % 3) * 4;
            f32x4 o;
            o.x = lds[row * V + swidx[wave][c0 + 0]] * swyh[wave][c0 + 0];
            o.y = lds[row * V + swidx[wave][c0 + 1]] * swyh[wave][c0 + 1];
            o.z = lds[row * V + swidx[wave][c0 + 2]] * swyh[wave][c0 + 2];
            o.w = lds[row * V + swidx[wave][c0 + 3]] * swyh[wave][c0 + 3];
            __builtin_nontemporal_store(o, &dst[f]);
        }
    } else {
        if (wave != 0) return;
        const int b2 = blockIdx.x - NBLK_G;
        const int n  = b2 / K;
        const int k  = b2 % K;
        if (lane < VK) swidx[0][lane] = idxbuf[n * VK + lane];
        const float* Ak = A + ((size_t)n * K + k) * V * V;
        for (int i = lane; i < V * V; i += 64) lds[i] = Ak[i];
        asm volatile("s_waitcnt vmcnt(0) lgkmcnt(0)" ::: "memory");
        for (int o = lane; o < VK * VK; o += 64) {
            const int a  = o / VK, bc = o % VK;
            const int ia = swidx[0][a], ib = swidx[0][bc];
            float ssum = 0.f;
            #pragma unroll
            for (int m = 0; m < V; ++m) ssum += lds[ia * V + m] * lds[m * V + ib];
            __builtin_nontemporal_store(ssum, &aout[((size_t)n * K + k) * VK * VK + o]);
        }
    }
}

extern "C" void kernel_launch(void* const* d_in, const int* in_sizes, int n_in,
                              void* d_out, int out_size, void* d_ws, size_t ws_size,
                              hipStream_t stream) {
    const float* x = (const float*)d_in[0];
    const float* A = (const float*)d_in[1];
    const float* p = (const float*)d_in[2];

    float* xout = (float*)d_out;                       // N*CT*VK floats
    float* aout = xout + (size_t)N * CT * VK;          // N*K*VK*VK floats

    char* ws = (char*)d_ws;
    float* partial_t = (float*)(ws);                   // 51200 floats [n][v][s]
    float* p2partial = (float*)(ws + 204800);          // 32 floats
    float* yhatbuf   = (float*)(ws + 204928);          // 768 floats
    int*   idxbuf    = (int*)  (ws + 208000);          // 768 ints
    ushort* xc       = (ushort*)(ws + XC_OFF);         // bf16 transposed copy

    const bool use_xc = ws_size >= XC_OFF + XC_BYTES;

    if (use_xc) {
        k_scores<true><<<N * SPLIT, 256, 0, stream>>>(x, p, partial_t, p2partial, xc);
        k_topk<<<N, 64, 0, stream>>>(partial_t, p2partial, idxbuf, yhatbuf);
        k_gather_xc<<<NBLK_G + N * K, 256, 0, stream>>>(xc, A, idxbuf, yhatbuf, xout, aout);
    } else {
        k_scores<false><<<N * SPLIT, 256, 0, stream>>>(x, p, partial_t, p2partial, xc);
        k_topk<<<N, 64, 0, stream>>>(partial_t, p2partial, idxbuf, yhatbuf);
        k_gather_aout<<<NBLK_G + N * K, 256, 0, stream>>>(x, A, idxbuf, yhatbuf, xout, aout);
    }
}

// Round 9
// 95.708 us; speedup vs baseline: 1.0577x; 1.0540x over previous
//
#include <hip/hip_runtime.h>
#include <hip/hip_bf16.h>
#include <math.h>

// Problem constants (fixed by setup_inputs)
constexpr int N  = 64;
constexpr int V  = 25;
constexpr int K  = 3;
constexpr int CT = 32768;            // C*T
constexpr int VK = 12;               // int(0.5 * 25)
constexpr int SPLIT = 64;            // chunks per sample
constexpr int CHUNK = CT / SPLIT;    // 512 ct per chunk
constexpr int ROWS  = 256;           // rows staged per LDS tile (64 per wave)
constexpr int TILES = CHUNK / ROWS;  // 2
constexpr int NBLK_X = N * SPLIT;    // 4096 chunk blocks (phase 1 and phase 2)
constexpr int NBLK_G6 = N * (CT / ROWS);  // 8192 fallback gather blocks

typedef float    f32x4 __attribute__((ext_vector_type(4)));
typedef unsigned u32x4 __attribute__((ext_vector_type(4)));

// ---------------- ws layout (bytes) ----------------
// partial_t : N*V*SPLIT floats = 102400 @ 0      (409600 B)  layout [n][v][s]
// p2partial : SPLIT floats @ 409600               (256 B)
// y_hat     : N*VK floats @ 409856                (3072 B)
// idx       : N*VK ints  @ 412928                 (3072 B)
// xc        : N*SPLIT*V*CHUNK ushorts @ 417792    (104857600 B)  [n][s][v][512] bf16
constexpr size_t XC_OFF   = 417792;
constexpr size_t XC_BYTES = (size_t)N * V * CT * sizeof(ushort);

__device__ __forceinline__ float bf2f(ushort us) {
    return __uint_as_float((unsigned)us << 16);
}

__device__ __forceinline__ void gload_lds16(const float* g, float* l) {
    // async global->LDS DMA: 16B per lane; global src per-lane, LDS dest uniform+lane*16
    __builtin_amdgcn_global_load_lds(
        (const __attribute__((address_space(1))) void*)g,
        (__attribute__((address_space(3))) void*)l, 16, 0, 0);
}

// Wave stages its own 64 rows (1600 floats = 400 float4s). Region is wave-exclusive.
__device__ __forceinline__ void stage_wave(const float* __restrict__ gsrc, float* ldsbuf,
                                           int wave, int lane) {
    const float* gw = gsrc + (size_t)wave * 1600;
    float* lw = ldsbuf + wave * 1600;
    #pragma unroll
    for (int i = 0; i < 6; ++i)
        gload_lds16(gw + (size_t)(i * 64 + lane) * 4, lw + i * 256);
    if (lane < 16)
        gload_lds16(gw + (size_t)(384 + lane) * 4, lw + 384 * 4);
}

// Phase 1: partial raw dots + (optionally) bf16 transposed chunk, accumulated in
// LDS and written out contiguously (25.6 KB NT stream per block).
template <bool WRITE_XC>
__global__ __launch_bounds__(256) void k_scores(const float* __restrict__ x,
                                                const float* __restrict__ p,
                                                float* __restrict__ partial_t,
                                                float* __restrict__ p2partial,
                                                ushort* __restrict__ xc) {
    const int n = blockIdx.x >> 6;        // / SPLIT
    const int s = blockIdx.x & 63;        // % SPLIT
    const int ct0 = s * CHUNK;
    const float* xn = x + (size_t)n * CT * V;
    const int tid = threadIdx.x, wave = tid >> 6, lane = tid & 63;

    __shared__ __align__(16) float  lds[ROWS * V];       // 25600 B staging
    __shared__ __align__(16) ushort xcl[V * CHUNK];      // 25600 B transposed chunk

    float acc[V];
    #pragma unroll
    for (int v = 0; v < V; ++v) acc[v] = 0.f;
    float psq = 0.f;

    for (int t = 0; t < TILES; ++t) {
        const int base_ct = ct0 + t * ROWS;
        // WAR: this wave's ds_reads of staging must retire before DMA overwrite
        asm volatile("s_waitcnt lgkmcnt(0)" ::: "memory");
        stage_wave(xn + (size_t)base_ct * V, lds, wave, lane);
        asm volatile("s_waitcnt vmcnt(0)" ::: "memory");

        const float pv = p[base_ct + tid];
        psq += pv * pv;
        const float* row = lds + tid * V;     // stride 25: bank-conflict-free
        #pragma unroll
        for (int v = 0; v < V; ++v) acc[v] += row[v] * pv;

        if (WRITE_XC) {
            // wave-local packed transpose of its own 64 rows into xcl[v][ct_local]
            const float* wrows = lds + wave * 64 * V;
            #pragma unroll
            for (int it = 0; it < 4; ++it) {
                const int pq = lane + it * 64;        // (v, octet) pairs, 200 total
                if (pq < V * 8) {
                    const int v = pq >> 3, o = pq & 7;
                    const float* src = wrows + o * 8 * V + v;
                    unsigned u0, u1, u2, u3;
                    asm("v_cvt_pk_bf16_f32 %0, %1, %2" : "=v"(u0) : "v"(src[0 * V]), "v"(src[1 * V]));
                    asm("v_cvt_pk_bf16_f32 %0, %1, %2" : "=v"(u1) : "v"(src[2 * V]), "v"(src[3 * V]));
                    asm("v_cvt_pk_bf16_f32 %0, %1, %2" : "=v"(u2) : "v"(src[4 * V]), "v"(src[5 * V]));
                    asm("v_cvt_pk_bf16_f32 %0, %1, %2" : "=v"(u3) : "v"(src[6 * V]), "v"(src[7 * V]));
                    u32x4 pk = {u0, u1, u2, u3};
                    *(u32x4*)(xcl + v * CHUNK + t * ROWS + wave * 64 + o * 8) = pk;  // 16B
                }
            }
        }
    }

    #pragma unroll
    for (int v = 0; v < V; ++v) {
        float a = acc[v];
        #pragma unroll
        for (int off = 32; off > 0; off >>= 1) a += __shfl_down(a, off);
        acc[v] = a;
    }
    #pragma unroll
    for (int off = 32; off > 0; off >>= 1) psq += __shfl_down(psq, off);

    __shared__ float red[4][V];
    __shared__ float redp[4];
    if (lane == 0) {
        #pragma unroll
        for (int v = 0; v < V; ++v) red[wave][v] = acc[v];
        redp[wave] = psq;
    }
    __syncthreads();     // covers red[] AND all waves' xcl writes

    if (tid < V) {
        partial_t[((size_t)n * V + tid) * SPLIT + s] =
            red[0][tid] + red[1][tid] + red[2][tid] + red[3][tid];
    }
    if (tid == V && n == 0) {
        p2partial[s] = redp[0] + redp[1] + redp[2] + redp[3];
    }

    if (WRITE_XC) {
        // one contiguous 25.6-KB NT stream per block: [n][s][v][512]
        const u32x4* srcv = (const u32x4*)xcl;
        u32x4* dstg = (u32x4*)(xc + (size_t)(n * SPLIT + s) * V * CHUNK);
        for (int i = tid; i < V * CHUNK / 8; i += 256)      // 1600 u32x4s
            __builtin_nontemporal_store(srcv[i], &dstg[i]);
    }
}

// Top-12 per sample (stable desc on raw sums — monotone-equivalent under the
// positive normalization scale), y_hat = sigmoid(normalized). 64 x 64.
__global__ __launch_bounds__(64) void k_topk(const float* __restrict__ partial_t,
                                             const float* __restrict__ p2partial,
                                             int* __restrict__ idxbuf,
                                             float* __restrict__ yhatbuf) {
    const int n = blockIdx.x, lane = threadIdx.x;
    float s2 = 0.f;
    #pragma unroll
    for (int i = 0; i < SPLIT; ++i) s2 += p2partial[i];

    float my = 0.f;
    if (lane < V) {
        const float4* pb = (const float4*)(partial_t + ((size_t)n * V + lane) * SPLIT);
        #pragma unroll
        for (int i = 0; i < SPLIT / 4; ++i) {
            float4 q = pb[i];
            my += q.x + q.y + q.z + q.w;
        }
    }
    int rank = 0;
    #pragma unroll
    for (int u = 0; u < V; ++u) {
        const float yu = __shfl(my, u);
        if (yu > my || (yu == my && u < lane)) ++rank;
    }
    if (lane < V && rank < VK) {
        idxbuf[n * VK + rank]  = lane;
        yhatbuf[n * VK + rank] = 1.0f / (1.0f + expf(-my * rsqrtf(s2)));
    }
}

// Phase 2 (fast path): block = one (n,s) chunk. DMA the 12 kept bf16 rows
// (12 x 1 KB, all within one 25.6-KB window) into LDS, emit 24.5 KB contiguous NT.
// blocks [0,4096): x_out. blocks [4096,4288): A_out (wave 0).
__global__ __launch_bounds__(256) void k_gather_xc(const ushort* __restrict__ xc,
                                                   const float* __restrict__ A,
                                                   const int* __restrict__ idxbuf,
                                                   const float* __restrict__ yhatbuf,
                                                   float* __restrict__ xout,
                                                   float* __restrict__ aout) {
    const int tid = threadIdx.x, wave = tid >> 6, lane = tid & 63;
    __shared__ __align__(16) ushort xl[VK * CHUNK];      // 12288 B
    __shared__ float syh[VK];

    if (blockIdx.x < (unsigned)NBLK_X) {
        const int n = blockIdx.x >> 6, s = blockIdx.x & 63;
        const ushort* xcs = xc + (size_t)(n * SPLIT + s) * V * CHUNK;

        // each wave DMAs 3 kept rows (1 KB each, uniform row index via readfirstlane)
        #pragma unroll
        for (int jj = 0; jj < 3; ++jj) {
            const int j  = wave * 3 + jj;
            const int ia = __builtin_amdgcn_readfirstlane(idxbuf[n * VK + j]);
            gload_lds16((const float*)(xcs + (size_t)ia * CHUNK + lane * 8),
                        (float*)(xl + j * CHUNK));
        }
        if (tid < VK) syh[tid] = yhatbuf[n * VK + tid];
        asm volatile("s_waitcnt vmcnt(0)" ::: "memory");
        __syncthreads();

        // 512 ct x 12 = 1536 f4s; thread writes f = tid + 256*jj (coalesced NT)
        f32x4* dst = (f32x4*)(xout + ((size_t)n * CT + s * CHUNK) * VK);
        #pragma unroll
        for (int jj = 0; jj < 6; ++jj) {
            const int f  = tid + jj * 256;
            const int ct = f / 3;
            const int c0 = (f % 3) * 4;
            f32x4 o;
            o.x = bf2f(xl[(c0 + 0) * CHUNK + ct]) * syh[c0 + 0];
            o.y = bf2f(xl[(c0 + 1) * CHUNK + ct]) * syh[c0 + 1];
            o.z = bf2f(xl[(c0 + 2) * CHUNK + ct]) * syh[c0 + 2];
            o.w = bf2f(xl[(c0 + 3) * CHUNK + ct]) * syh[c0 + 3];
            __builtin_nontemporal_store(o, &dst[f]);
        }
    } else {
        if (wave != 0) return;                     // tiny blocks: single wave
        __shared__ float ldsA[V * V];
        __shared__ int   sidx[VK];
        const int b2 = blockIdx.x - NBLK_X;        // [0, 192)
        const int n  = b2 / K;
        const int k  = b2 % K;
        if (lane < VK) sidx[lane] = idxbuf[n * VK + lane];
        const float* Ak = A + ((size_t)n * K + k) * V * V;
        for (int i = lane; i < V * V; i += 64) ldsA[i] = Ak[i];
        asm volatile("s_waitcnt vmcnt(0) lgkmcnt(0)" ::: "memory");
        for (int o = lane; o < VK * VK; o += 64) {
            const int a  = o / VK, bc = o % VK;
            const int ia = sidx[a], ib = sidx[bc];
            float ssum = 0.f;
            #pragma unroll
            for (int m = 0; m < V; ++m) ssum += ldsA[ia * V + m] * ldsA[m * V + ib];
            __builtin_nontemporal_store(ssum, &aout[((size_t)n * K + k) * VK * VK + o]);
        }
    }
}

// Fallback phase 2 (ws too small for xc): round-6 structure, re-reads fp32 x.
__global__ __launch_bounds__(256) void k_gather_aout(const float* __restrict__ x,
                                                     const float* __restrict__ A,
                                                     const int* __restrict__ idxbuf,
                                                     const float* __restrict__ yhatbuf,
                                                     float* __restrict__ xout,
                                                     float* __restrict__ aout) {
    __shared__ float lds[ROWS * V];
    __shared__ int   swidx[4][VK];
    __shared__ float swyh[4][VK];
    const int tid = threadIdx.x, wave = tid >> 6, lane = tid & 63;

    if (blockIdx.x < (unsigned)NBLK_G6) {
        const int n  = blockIdx.x >> 7;
        const int r0 = (blockIdx.x & 127) << 8;
        stage_wave(x + ((size_t)n * CT + r0) * V, lds, wave, lane);
        if (lane < VK) {
            swidx[wave][lane] = idxbuf[n * VK + lane];
            swyh[wave][lane]  = yhatbuf[n * VK + lane];
        }
        asm volatile("s_waitcnt vmcnt(0) lgkmcnt(0)" ::: "memory");
        f32x4* dst = (f32x4*)(xout + ((size_t)n * CT + r0) * VK);
        #pragma unroll
        for (int j = 0; j < 3; ++j) {
            const int f   = 192 * wave + 64 * j + lane;
            const int row = f / 3;
            const int c0  = (f % 3) * 4;
            f32x4 o;
            o.x = lds[row * V + swidx[wave][c0 + 0]] * swyh[wave][c0 + 0];
            o.y = lds[row * V + swidx[wave][c0 + 1]] * swyh[wave][c0 + 1];
            o.z = lds[row * V + swidx[wave][c0 + 2]] * swyh[wave][c0 + 2];
            o.w = lds[row * V + swidx[wave][c0 + 3]] * swyh[wave][c0 + 3];
            __builtin_nontemporal_store(o, &dst[f]);
        }
    } else {
        if (wave != 0) return;
        const int b2 = blockIdx.x - NBLK_G6;
        const int n  = b2 / K;
        const int k  = b2 % K;
        if (lane < VK) swidx[0][lane] = idxbuf[n * VK + lane];
        const float* Ak = A + ((size_t)n * K + k) * V * V;
        for (int i = lane; i < V * V; i += 64) lds[i] = Ak[i];
        asm volatile("s_waitcnt vmcnt(0) lgkmcnt(0)" ::: "memory");
        for (int o = lane; o < VK * VK; o += 64) {
            const int a  = o / VK, bc = o % VK;
            const int ia = swidx[0][a], ib = swidx[0][bc];
            float ssum = 0.f;
            #pragma unroll
            for (int m = 0; m < V; ++m) ssum += lds[ia * V + m] * lds[m * V + ib];
            __builtin_nontemporal_store(ssum, &aout[((size_t)n * K + k) * VK * VK + o]);
        }
    }
}

extern "C" void kernel_launch(void* const* d_in, const int* in_sizes, int n_in,
                              void* d_out, int out_size, void* d_ws, size_t ws_size,
                              hipStream_t stream) {
    const float* x = (const float*)d_in[0];
    const float* A = (const float*)d_in[1];
    const float* p = (const float*)d_in[2];

    float* xout = (float*)d_out;                       // N*CT*VK floats
    float* aout = xout + (size_t)N * CT * VK;          // N*K*VK*VK floats

    char* ws = (char*)d_ws;
    float* partial_t = (float*)(ws);                   // [n][v][s]
    float* p2partial = (float*)(ws + 409600);
    float* yhatbuf   = (float*)(ws + 409856);
    int*   idxbuf    = (int*)  (ws + 412928);
    ushort* xc       = (ushort*)(ws + XC_OFF);         // [n][s][v][512] bf16

    const bool use_xc = ws_size >= XC_OFF + XC_BYTES;

    if (use_xc) {
        k_scores<true><<<NBLK_X, 256, 0, stream>>>(x, p, partial_t, p2partial, xc);
        k_topk<<<N, 64, 0, stream>>>(partial_t, p2partial, idxbuf, yhatbuf);
        k_gather_xc<<<NBLK_X + N * K, 256, 0, stream>>>(xc, A, idxbuf, yhatbuf, xout, aout);
    } else {
        k_scores<false><<<NBLK_X, 256, 0, stream>>>(x, p, partial_t, p2partial, xc);
        k_topk<<<N, 64, 0, stream>>>(partial_t, p2partial, idxbuf, yhatbuf);
        k_gather_aout<<<NBLK_G6 + N * K, 256, 0, stream>>>(x, A, idxbuf, yhatbuf, xout, aout);
    }
}

// Round 10
// 88.911 us; speedup vs baseline: 1.1385x; 1.0765x over previous
//
#include <hip/hip_runtime.h>
#include <hip/hip_bf16.h>
#include <math.h>

// Problem constants (fixed by setup_inputs)
constexpr int N  = 64;
constexpr int V  = 25;
constexpr int K  = 3;
constexpr int CT = 32768;            // C*T
constexpr int VK = 12;               // int(0.5 * 25)
constexpr int SPLIT = 32;            // score-pass split along ct per sample
constexpr int ROWS  = 256;           // rows per LDS tile (64 rows per wave)
constexpr int CHUNK = CT / SPLIT;    // 1024
constexpr int TILES = CHUNK / ROWS;  // 4
constexpr int NBLK_G = N * (CT / ROWS);   // 8192 gather blocks

typedef float f32x4 __attribute__((ext_vector_type(4)));   // NT-store-legal float4

// ---------------- ws layout (bytes) ----------------
// partial_t : N*V*SPLIT floats = 51200 @ 0       (204800 B)  layout [n][v][s]
// p2partial : SPLIT floats @ 204800               (128 B)
// y_hat     : N*VK floats @ 204928                (3072 B)
// idx       : N*VK ints  @ 208000                 (3072 B)

__device__ __forceinline__ void gload_lds16(const float* g, float* l) {
    // async global->LDS DMA: 16B per lane; LDS dest = wave-uniform base + lane*16
    __builtin_amdgcn_global_load_lds(
        (const __attribute__((address_space(1))) void*)g,
        (__attribute__((address_space(3))) void*)l, 16, 0, 0);
}

// Wave stages its own 64 rows (1600 floats = 400 float4s): 6 full issues + 16-lane
// tail = exactly 7 vmcnt increments per call. Region is wave-exclusive.
__device__ __forceinline__ void stage_wave(const float* __restrict__ gsrc, float* ldsbuf,
                                           int wave, int lane) {
    const float* gw = gsrc + (size_t)wave * 1600;
    float* lw = ldsbuf + wave * 1600;
    #pragma unroll
    for (int i = 0; i < 6; ++i)
        gload_lds16(gw + (size_t)(i * 64 + lane) * 4, lw + i * 256);
    if (lane < 16)
        gload_lds16(gw + (size_t)(384 + lane) * 4, lw + 384 * 4);
}

// Kernel 1: partial raw dots, per-wave double-buffered with counted vmcnt (never
// drains mid-loop). partial_t[n][v][s] = sum over ct-slice of x[n,ct,v]*p[ct].
__global__ __launch_bounds__(256) void k_scores(const float* __restrict__ x,
                                                const float* __restrict__ p,
                                                float* __restrict__ partial_t,
                                                float* __restrict__ p2partial) {
    const int n = blockIdx.x / SPLIT;
    const int s = blockIdx.x % SPLIT;
    const int ct0 = s * CHUNK;
    const float* xn = x + (size_t)n * CT * V;
    const int tid = threadIdx.x, wave = tid >> 6, lane = tid & 63;

    __shared__ float lds[2][ROWS * V];       // 2 x 25600 B

    // preload all p values BEFORE the DMA chain so vmcnt counting stays exact
    float pv[TILES];
    #pragma unroll
    for (int t = 0; t < TILES; ++t) pv[t] = p[ct0 + t * ROWS + tid];

    stage_wave(xn + (size_t)(ct0 + 0 * ROWS) * V, lds[0], wave, lane);
    stage_wave(xn + (size_t)(ct0 + 1 * ROWS) * V, lds[1], wave, lane);

    float acc[V];
    #pragma unroll
    for (int v = 0; v < V; ++v) acc[v] = 0.f;
    float psq = 0.f;

    #pragma unroll
    for (int t = 0; t < TILES; ++t) {
        // oldest 7 loads (tile t) complete; up to 7 (tile t+1) stay in flight
        if (t < TILES - 1) asm volatile("s_waitcnt vmcnt(7)" ::: "memory");
        else               asm volatile("s_waitcnt vmcnt(0)" ::: "memory");

        const float pvt = pv[t];
        psq += pvt * pvt;
        const float* row = lds[t & 1] + tid * V;   // stride 25: bank-conflict-free
        #pragma unroll
        for (int v = 0; v < V; ++v) acc[v] += row[v] * pvt;

        if (t + 2 < TILES) {
            // WAR: our ds_reads of this buffer must retire before DMA overwrites it
            asm volatile("s_waitcnt lgkmcnt(0)" ::: "memory");
            stage_wave(xn + (size_t)(ct0 + (t + 2) * ROWS) * V, lds[t & 1], wave, lane);
        }
    }

    #pragma unroll
    for (int v = 0; v < V; ++v) {
        float a = acc[v];
        #pragma unroll
        for (int off = 32; off > 0; off >>= 1) a += __shfl_down(a, off);
        acc[v] = a;
    }
    #pragma unroll
    for (int off = 32; off > 0; off >>= 1) psq += __shfl_down(psq, off);

    __shared__ float red[4][V];
    __shared__ float redp[4];
    if (lane == 0) {
        #pragma unroll
        for (int v = 0; v < V; ++v) red[wave][v] = acc[v];
        redp[wave] = psq;
    }
    __syncthreads();
    if (tid < V) {
        partial_t[((size_t)n * V + tid) * SPLIT + s] =
            red[0][tid] + red[1][tid] + red[2][tid] + red[3][tid];
    }
    if (tid == V && n == 0) {
        p2partial[s] = redp[0] + redp[1] + redp[2] + redp[3];
    }
}

// Kernel 2: per-sample top-12 (stable desc on raw sums — monotone-equivalent under
// the positive normalization scale), y_hat = sigmoid(normalized). 64 x 64.
__global__ __launch_bounds__(64) void k_topk(const float* __restrict__ partial_t,
                                             const float* __restrict__ p2partial,
                                             int* __restrict__ idxbuf,
                                             float* __restrict__ yhatbuf) {
    const int n = blockIdx.x, lane = threadIdx.x;
    float s2 = 0.f;
    #pragma unroll
    for (int i = 0; i < SPLIT; ++i) s2 += p2partial[i];

    float my = 0.f;
    if (lane < V) {
        const float4* pb = (const float4*)(partial_t + ((size_t)n * V + lane) * SPLIT);
        #pragma unroll
        for (int i = 0; i < SPLIT / 4; ++i) {
            float4 q = pb[i];
            my += q.x + q.y + q.z + q.w;
        }
    }
    int rank = 0;
    #pragma unroll
    for (int u = 0; u < V; ++u) {
        const float yu = __shfl(my, u);
        if (yu > my || (yu == my && u < lane)) ++rank;
    }
    if (lane < V && rank < VK) {
        idxbuf[n * VK + rank]  = lane;
        yhatbuf[n * VK + rank] = 1.0f / (1.0f + expf(-my * rsqrtf(s2)));
    }
}

// Kernel 3: blocks [0,8192): gather+scale, barrier-free per-wave regions, NT stores
//           (xout never re-read -> don't pollute caches).
//           blocks [8192,8384): A_out[n,k,a,b] = sum_m A[n,k,ia,m]*A[n,k,m,ib], wave 0.
__global__ __launch_bounds__(256) void k_gather_aout(const float* __restrict__ x,
                                                     const float* __restrict__ A,
                                                     const int* __restrict__ idxbuf,
                                                     const float* __restrict__ yhatbuf,
                                                     float* __restrict__ xout,
                                                     float* __restrict__ aout) {
    __shared__ float lds[ROWS * V];          // 25600 B (aout path uses first 625)
    __shared__ int   swidx[4][VK];
    __shared__ float swyh[4][VK];
    const int tid = threadIdx.x, wave = tid >> 6, lane = tid & 63;

    if (blockIdx.x < (unsigned)NBLK_G) {
        const int n  = blockIdx.x >> 7;          // 128 tiles per sample
        const int r0 = (blockIdx.x & 127) << 8;  // row base within sample

        // 1) issue this wave's 64-row stage DMA
        stage_wave(x + ((size_t)n * CT + r0) * V, lds, wave, lane);
        // 2) fetch idx/yhat (L2-hot) into wave-local LDS scratch while DMA flies
        if (lane < VK) {
            swidx[wave][lane] = idxbuf[n * VK + lane];
            swyh[wave][lane]  = yhatbuf[n * VK + lane];
        }
        // 3) same-wave completion: DMA + scratch ds_writes
        asm volatile("s_waitcnt vmcnt(0) lgkmcnt(0)" ::: "memory");

        // 4) wave w writes output f4s [192w,192w+192) covering its own 64 rows
        f32x4* dst = (f32x4*)(xout + ((size_t)n * CT + r0) * VK);
        #pragma unroll
        for (int j = 0; j < 3; ++j) {
            const int f   = 192 * wave + 64 * j + lane;
            const int row = f / 3;
            const int c0  = (f % 3) * 4;
            f32x4 o;
            o.x = lds[row * V + swidx[wave][c0 + 0]] * swyh[wave][c0 + 0];
            o.y = lds[row * V + swidx[wave][c0 + 1]] * swyh[wave][c0 + 1];
            o.z = lds[row * V + swidx[wave][c0 + 2]] * swyh[wave][c0 + 2];
            o.w = lds[row * V + swidx[wave][c0 + 3]] * swyh[wave][c0 + 3];
            __builtin_nontemporal_store(o, &dst[f]);   // coalesced, no-allocate
        }
    } else {
        if (wave != 0) return;                   // tiny blocks: single wave, no barrier
        const int b2 = blockIdx.x - NBLK_G;      // [0, 192)
        const int n  = b2 / K;
        const int k  = b2 % K;
        if (lane < VK) swidx[0][lane] = idxbuf[n * VK + lane];
        const float* Ak = A + ((size_t)n * K + k) * V * V;
        for (int i = lane; i < V * V; i += 64) lds[i] = Ak[i];
        asm volatile("s_waitcnt vmcnt(0) lgkmcnt(0)" ::: "memory");
        for (int o = lane; o < VK * VK; o += 64) {
            const int a  = o / VK, bc = o % VK;
            const int ia = swidx[0][a], ib = swidx[0][bc];
            float ssum = 0.f;
            #pragma unroll
            for (int m = 0; m < V; ++m) ssum += lds[ia * V + m] * lds[m * V + ib];
            __builtin_nontemporal_store(ssum, &aout[((size_t)n * K + k) * VK * VK + o]);
        }
    }
}

extern "C" void kernel_launch(void* const* d_in, const int* in_sizes, int n_in,
                              void* d_out, int out_size, void* d_ws, size_t ws_size,
                              hipStream_t stream) {
    const float* x = (const float*)d_in[0];
    const float* A = (const float*)d_in[1];
    const float* p = (const float*)d_in[2];

    float* xout = (float*)d_out;                       // N*CT*VK floats
    float* aout = xout + (size_t)N * CT * VK;          // N*K*VK*VK floats

    char* ws = (char*)d_ws;
    float* partial_t = (float*)(ws);                   // 51200 floats [n][v][s]
    float* p2partial = (float*)(ws + 204800);          // 32 floats
    float* yhatbuf   = (float*)(ws + 204928);          // 768 floats
    int*   idxbuf    = (int*)  (ws + 208000);          // 768 ints

    k_scores<<<N * SPLIT, 256, 0, stream>>>(x, p, partial_t, p2partial);
    k_topk<<<N, 64, 0, stream>>>(partial_t, p2partial, idxbuf, yhatbuf);
    k_gather_aout<<<NBLK_G + N * K, 256, 0, stream>>>(x, A, idxbuf, yhatbuf, xout, aout);
}